// Round 7
// baseline (164.230 us; speedup 1.0000x reference)
//
#include <hip/hip_runtime.h>
#include <math.h>

// CPC loss, MI355X. B=16 T=512 D=256, horizons {1,5,21}, 128 negatives, temp 0.07.
// ws: [0,4MB) az f16 | [4MB,+2MB) ani int8 | [6MB,+384KB) Wh f16 | [6.375MB,+12MB) zp f16
constexpr int Bc = 16, Tc = 512, Dc = 256, NNEGc = 128, BTc = Bc * Tc;
constexpr float TEMP_INV = 1.0f / 0.07f;
constexpr float QSCALE = TEMP_INV / (127.0f * 127.0f);

typedef __attribute__((ext_vector_type(8))) short short8;
typedef __attribute__((ext_vector_type(4))) float f32x4;
typedef __attribute__((ext_vector_type(4))) _Float16 f16x4;
typedef __attribute__((ext_vector_type(2))) _Float16 h2;

struct HP { int L, N, kh; float scale; long long nxOff; };
struct HP3 { HP h[3]; };

__device__ inline unsigned packh2(float a, float b) {
    h2 p = {(_Float16)a, (_Float16)b};
    return __builtin_bit_cast(unsigned, p);
}
__device__ inline float dot2(unsigned a, unsigned b, float c) {
#if __has_builtin(__builtin_amdgcn_fdot2)
    return __builtin_amdgcn_fdot2(__builtin_bit_cast(h2, a), __builtin_bit_cast(h2, b), c, false);
#else
    h2 x = __builtin_bit_cast(h2, a), y = __builtin_bit_cast(h2, b);
    return c + (float)x.x * (float)y.x + (float)x.y * (float)y.y;
#endif
}
__device__ inline int sdot4(unsigned a, unsigned b, int c) {
#if __has_builtin(__builtin_amdgcn_sdot4)
    return __builtin_amdgcn_sdot4((int)a, (int)b, c, false);
#else
    c += (int)(char)(a) * (int)(char)(b);
    c += (int)(char)(a >> 8) * (int)(char)(b >> 8);
    c += (int)(char)(a >> 16) * (int)(char)(b >> 16);
    c += (int)(char)(a >> 24) * (int)(char)(b >> 24);
    return c;
#endif
}
// quantize 4 normalized floats (|v|<=1) to packed int8, scale 127
__device__ inline unsigned q4i8(float a, float b, float c, float d) {
    int qa = (int)rintf(a * 127.0f), qb = (int)rintf(b * 127.0f);
    int qc = (int)rintf(c * 127.0f), qd = (int)rintf(d * 127.0f);
    return (qa & 0xff) | ((qb & 0xff) << 8) | ((qc & 0xff) << 16) | ((unsigned)qd << 24);
}

// Normalize all BT rows -> az (f16, 512 B/row) + ani (int8, 256 B/row);
// first 96 blocks also convert W to f16; block 0 zeroes out[0].
__global__ __launch_bounds__(256) void k_norm(const float* __restrict__ z,
                                              const float* __restrict__ preds,
                                              unsigned* __restrict__ az,
                                              unsigned* __restrict__ ani,
                                              unsigned* __restrict__ Wh,
                                              float* __restrict__ out) {
    if (blockIdx.x == 0 && threadIdx.x == 0) out[0] = 0.0f;
    if (blockIdx.x < 96) {
        int base = blockIdx.x * 2048 + threadIdx.x * 8;
        float4 w0 = reinterpret_cast<const float4*>(preds + base)[0];
        float4 w1 = reinterpret_cast<const float4*>(preds + base)[1];
        uint4 o;
        o.x = packh2(w0.x, w0.y); o.y = packh2(w0.z, w0.w);
        o.z = packh2(w1.x, w1.y); o.w = packh2(w1.z, w1.w);
        reinterpret_cast<uint4*>(Wh)[blockIdx.x * 256 + threadIdx.x] = o;
    }
    int wid = threadIdx.x >> 6, lane = threadIdx.x & 63;
    int row = blockIdx.x * 4 + wid;
    float4 v = reinterpret_cast<const float4*>(z)[row * 64 + lane];
    float s = v.x * v.x + v.y * v.y + v.z * v.z + v.w * v.w;
#pragma unroll
    for (int off = 32; off; off >>= 1) s += __shfl_xor(s, off, 64);
    float inv = 1.0f / fmaxf(sqrtf(s), 1e-12f);
    float a = v.x * inv, b = v.y * inv, c = v.z * inv, d = v.w * inv;
    reinterpret_cast<uint2*>(az)[row * 64 + lane] = make_uint2(packh2(a, b), packh2(c, d));
    ani[row * 64 + lane] = q4i8(a, b, c, d);
}

// LDS-tiled f16 MFMA GEMM with XOR-swizzled LDS columns.
// Block = 64x64, K=256 one pass. grid = (8192/64, 768/64), 4 waves.
__global__ __launch_bounds__(256) void k_gemm(const unsigned* __restrict__ az,
                                              const unsigned* __restrict__ Wh,
                                              _Float16* __restrict__ zp) {
    __shared__ uint4 As[2048];
    __shared__ uint4 Bs[2048];
    int wave = threadIdx.x >> 6, lane = threadIdx.x & 63;
    int t = threadIdx.x;
    int m0 = blockIdx.x * 64, g0 = blockIdx.y * 64;
    const uint4* A4 = reinterpret_cast<const uint4*>(az) + (size_t)m0 * 32;
    const uint4* B4 = reinterpret_cast<const uint4*>(Wh) + (size_t)g0 * 32;
#pragma unroll
    for (int i = 0; i < 8; ++i) {
        int f = i * 256 + t;
        int r = f >> 5, c = f & 31;
        int sw = r * 32 + ((c ^ r) & 31);
        As[sw] = A4[f];
        Bs[sw] = B4[f];
    }
    __syncthreads();
    int mrow = lane & 15, kq = lane >> 4;
    f32x4 acc[4] = {f32x4{0,0,0,0}, f32x4{0,0,0,0}, f32x4{0,0,0,0}, f32x4{0,0,0,0}};
    int arow = wave * 16 + mrow;
#pragma unroll
    for (int kb = 0; kb < 8; ++kb) {
        int col = kb * 4 + kq;
        uint4 ua = As[arow * 32 + ((col ^ arow) & 31)];
        short8 a = __builtin_bit_cast(short8, ua);
#pragma unroll
        for (int nt = 0; nt < 4; ++nt) {
            int brow = nt * 16 + mrow;
            uint4 ub = Bs[brow * 32 + ((col ^ brow) & 31)];
            acc[nt] = __builtin_amdgcn_mfma_f32_16x16x32_f16(
                a, __builtin_bit_cast(short8, ub), acc[nt], 0, 0, 0);
        }
    }
    // C/D: col(=g) = lane&15, row(=m offset) = kq*4 + r
#pragma unroll
    for (int nt = 0; nt < 4; ++nt) {
        int g = g0 + nt * 16 + mrow;
        int h = g >> 8, e = g & 255;
        _Float16* dst = zp + ((size_t)h * BTc + m0 + wave * 16 + kq * 4) * Dc + e;
#pragma unroll
        for (int r = 0; r < 4; ++r) dst[(size_t)r * Dc] = (_Float16)acc[nt][r];
    }
}

// One wave per row n. Negatives from int8 table (256 B/row): quad q -> negative
// p*16+q; 4 lanes x uint4 = one 64B line per chunk. v_dot4_i32_i8 inner loop
// (no decode), exact i32 accumulate, scale at the end. Double-buffered loads.
// Deferred softmax, 1 atomic/block.
__global__ __launch_bounds__(256, 4) void k_loss(const unsigned* __restrict__ az,
                                                 const unsigned* __restrict__ ani,
                                                 const _Float16* __restrict__ zp_base,
                                                 const int* __restrict__ nx_base,
                                                 float* __restrict__ out,
                                                 HP3 P) {
    HP hp = P.h[blockIdx.y];
    __shared__ unsigned zq[4][64];   // packed int8 z_pred, per wave
    __shared__ float partial[4];
    int wid = threadIdx.x >> 6, lane = threadIdx.x & 63;
    int q = lane >> 2, q4 = lane & 3;
    int n = blockIdx.x * 4 + wid;
    float contrib = 0.0f;
    if (n < hp.N) {
        int b = n / hp.L, l = n - b * hp.L;
        int row = b * Tc + l;
        // normalize z_pred row (f16)
        f16x4 hv = reinterpret_cast<const f16x4*>(
                       zp_base + ((size_t)blockIdx.y * BTc + row) * Dc)[lane];
        float4 v = make_float4((float)hv.x, (float)hv.y, (float)hv.z, (float)hv.w);
        float s = v.x * v.x + v.y * v.y + v.z * v.z + v.w * v.w;
#pragma unroll
        for (int off = 32; off; off >>= 1) s += __shfl_xor(s, off, 64);
        float inv = 1.0f / fmaxf(sqrtf(s), 1e-12f);
        v.x *= inv; v.y *= inv; v.z *= inv; v.w *= inv;
        // int8 copy into LDS (elems [4*lane, 4*lane+4))
        zq[wid][lane] = q4i8(v.x, v.y, v.z, v.w);

        // positive logit on the f16 table (full precision path)
        unsigned u0 = packh2(v.x, v.y), u1 = packh2(v.z, v.w);
        uint2 pw = reinterpret_cast<const uint2*>(az + (size_t)(row + hp.kh) * 128)[lane];
        float pd = dot2(pw.y, u1, dot2(pw.x, u0, 0.0f));
#pragma unroll
        for (int off = 32; off; off >>= 1) pd += __shfl_xor(pd, off, 64);
        float pos = pd * TEMP_INV;

        // all 8 gather indices up-front
        const int* nx = nx_base + hp.nxOff + (size_t)n * NNEGc;
        int i1 = nx[lane], i2 = nx[lane + 64];
        int idxp[8];
#pragma unroll
        for (int p = 0; p < 8; ++p)
            idxp[p] = __shfl(p < 4 ? i1 : i2, (p & 3) * 16 + q, 64);

        // quad-view of this row's int8 z_pred: chunk c = elems [(c*4+q4)*16, +16)
        uint4 zqv[4];
        const uint4* zl4 = reinterpret_cast<const uint4*>(zq[wid]);
#pragma unroll
        for (int c = 0; c < 4; ++c) zqv[c] = zl4[c * 4 + q4];

        const uint4* ni4 = reinterpret_cast<const uint4*>(ani);
        uint4 gb[2][2][4];
        float lg[8];
#define LOAD_PAIR(buf, p0)                                                   \
        _Pragma("unroll")                                                    \
        for (int pp = 0; pp < 2; ++pp)                                       \
            _Pragma("unroll")                                                \
            for (int c = 0; c < 4; ++c)                                      \
                gb[buf][pp][c] = ni4[(size_t)idxp[(p0) + pp] * 16 + c * 4 + q4];
#define COMP_PAIR(buf, p0)                                                   \
        _Pragma("unroll")                                                    \
        for (int pp = 0; pp < 2; ++pp) {                                     \
            int acc = 0;                                                     \
            _Pragma("unroll")                                                \
            for (int c = 0; c < 4; ++c) {                                    \
                uint4 g = gb[buf][pp][c];                                    \
                acc = sdot4(g.x, zqv[c].x, acc);                             \
                acc = sdot4(g.y, zqv[c].y, acc);                             \
                acc = sdot4(g.z, zqv[c].z, acc);                             \
                acc = sdot4(g.w, zqv[c].w, acc);                             \
            }                                                                \
            acc += __shfl_xor(acc, 1, 64);                                   \
            acc += __shfl_xor(acc, 2, 64);                                   \
            lg[(p0) + pp] = (float)acc * QSCALE;                             \
        }
        LOAD_PAIR(0, 0)
        LOAD_PAIR(1, 2)
        COMP_PAIR(0, 0)
        LOAD_PAIR(0, 4)
        COMP_PAIR(1, 2)
        LOAD_PAIR(1, 6)
        COMP_PAIR(0, 4)
        COMP_PAIR(1, 6)
#undef LOAD_PAIR
#undef COMP_PAIR
        float mm = lg[0];
#pragma unroll
        for (int p = 1; p < 8; ++p) mm = fmaxf(mm, lg[p]);
#pragma unroll
        for (int off = 32; off; off >>= 1) mm = fmaxf(mm, __shfl_xor(mm, off, 64));
        mm = fmaxf(mm, pos);
        float sl = 0.0f;
#pragma unroll
        for (int p = 0; p < 8; ++p) sl += __expf(lg[p] - mm);
#pragma unroll
        for (int off = 32; off; off >>= 1) sl += __shfl_xor(sl, off, 64);
        float S = sl * 0.25f + __expf(pos - mm);  // each neg replicated 4x per quad
        float lse = mm + __logf(S);
        contrib = (lse - pos) * hp.scale;
    }
    if (lane == 0) partial[wid] = contrib;
    __syncthreads();
    if (threadIdx.x == 0)
        atomicAdd(out, partial[0] + partial[1] + partial[2] + partial[3]);
}

extern "C" void kernel_launch(void* const* d_in, const int* in_sizes, int n_in,
                              void* d_out, int out_size, void* d_ws, size_t ws_size,
                              hipStream_t stream) {
    const float* z     = (const float*)d_in[0];
    const float* preds = (const float*)d_in[1];
    const int*   nidx  = (const int*)d_in[2];
    float* out = (float*)d_out;

    unsigned* az  = (unsigned*)d_ws;                                 // 4 MB
    unsigned* ani = (unsigned*)((char*)d_ws + (size_t)4194304);      // 2 MB
    unsigned* Wh  = (unsigned*)((char*)d_ws + (size_t)6291456);      // 384 KB
    _Float16* zp  = (_Float16*)((char*)d_ws + (size_t)6684672);      // 12 MB

    const int ks[3] = {1, 5, 21};
    double rw[3] = {1.0, 1.0 / sqrt(5.0), 1.0 / sqrt(21.0)};
    double tot = rw[0] + rw[1] + rw[2];

    HP3 P;
    int maxN = 0;
    for (int i = 0; i < 3; ++i) {
        int L = Tc - ks[i], N = Bc * L;
        P.h[i].L = L; P.h[i].N = N; P.h[i].kh = ks[i];
        P.h[i].scale = (float)(rw[i] / tot / (double)N);
        P.h[i].nxOff = (long long)i * BTc * NNEGc;
        if (N > maxN) maxN = N;
    }

    k_norm<<<BTc / 4, 256, 0, stream>>>(z, preds, az, ani, Wh, out);
    k_gemm<<<dim3(BTc / 64, (3 * Dc) / 64), 256, 0, stream>>>(az, Wh, zp);
    k_loss<<<dim3((maxN + 3) / 4, 3), 256, 0, stream>>>(az, ani, zp, nidx, out, P);
}